// Round 18
// baseline (405.242 us; speedup 1.0000x reference)
//
#include <hip/hip_runtime.h>
#include <math.h>

// ---------------------------------------------------------------------------
// b=1, S=1024, H=16, D=64, HID=1024. All f32; pos int32; out f32.
// Passing R10-R17 semantics (absmax 6.958e-3). This round (select_agg2 only):
//  (1) shifted radix digits [25:18]/[17:10]/[9:2]/[1:0] when all scores < 2.0
//      (bits[31:26] constant 0x0F for [2^-7,2), zeros exactly 0 -> monotone);
//      first pass spreads ~128 bins (was ~2) -> no atomic pileup, earlier exit.
//  (2) single-hypothesis aggregation fast path on non-ambiguous rows.
// Selection + output bit-identical.
// ---------------------------------------------------------------------------
#define NEGF  -1e30f
#define TAU   1e-6f

static __device__ __forceinline__ int imin(int a, int b) { return a < b ? a : b; }

// ---------------------------------------------------------------------------
// f32 GEMM, 64x64 tile, 256 threads, 4x4/thread, BK=16, sequential FMA over k.
// MODE 0: plain f32; 1: silu; 2: +eps*R residual. Batched via blockIdx.z.
// ---------------------------------------------------------------------------
template <int MODE>
__global__ __launch_bounds__(256) void gemm64(
    const float* __restrict__ A, const float* __restrict__ B, float* __restrict__ C,
    const float* __restrict__ R, const float* __restrict__ eps_p,
    int M, int N, int K, int lda, int ldb, int ldc,
    long sA, long sB, long sC)
{
  const int z = blockIdx.z;
  A += (long)z * sA;
  B += (long)z * sB;
  float* Cf = C + (long)z * sC;
  const float* Rz = (MODE == 2) ? (R + (long)z * sC) : nullptr;

  const int bm = blockIdx.x * 64;
  const int bn = blockIdx.y * 64;
  const int tid = threadIdx.x;
  const int r0 = (tid >> 4) * 4;
  const int c0 = (tid & 15) * 4;

  __shared__ float As[16][68];
  __shared__ float Bs[16][64];

  float acc[4][4] = {};

  const int ar = tid >> 2;
  const int ac = (tid & 3) * 4;
  const int br = tid >> 4;
  const int bc = (tid & 15) * 4;

  for (int kt = 0; kt < K; kt += 16) {
    float4 av = *(const float4*)(A + (long)(bm + ar) * lda + kt + ac);
    float4 bv = *(const float4*)(B + (long)(kt + br) * ldb + bn + bc);
    As[ac + 0][ar] = av.x;
    As[ac + 1][ar] = av.y;
    As[ac + 2][ar] = av.z;
    As[ac + 3][ar] = av.w;
    *(float4*)&Bs[br][bc] = bv;
    __syncthreads();
#pragma unroll
    for (int kk = 0; kk < 16; ++kk) {
      const float4 xa = *(const float4*)&As[kk][r0];
      const float4 yb = *(const float4*)&Bs[kk][c0];
      acc[0][0] += xa.x * yb.x; acc[0][1] += xa.x * yb.y; acc[0][2] += xa.x * yb.z; acc[0][3] += xa.x * yb.w;
      acc[1][0] += xa.y * yb.x; acc[1][1] += xa.y * yb.y; acc[1][2] += xa.y * yb.z; acc[1][3] += xa.y * yb.w;
      acc[2][0] += xa.z * yb.x; acc[2][1] += xa.z * yb.y; acc[2][2] += xa.z * yb.z; acc[2][3] += xa.z * yb.w;
      acc[3][0] += xa.w * yb.x; acc[3][1] += xa.w * yb.y; acc[3][2] += xa.w * yb.z; acc[3][3] += xa.w * yb.w;
    }
    __syncthreads();
  }

  const float ev = (MODE == 2) ? eps_p[0] : 0.0f;
#pragma unroll
  for (int e = 0; e < 4; ++e)
#pragma unroll
    for (int f = 0; f < 4; ++f) {
      const int r = bm + r0 + e;
      const int c = bn + c0 + f;
      float x = acc[e][f];
      if (MODE == 1) x = x / (1.0f + expf(-x));
      if (MODE == 2) x += ev * Rz[(long)r * ldc + c];
      Cf[(long)r * ldc + c] = x;
    }
}

// ---------------------------------------------------------------------------
// Fused QKV projection, 1024^3 x3, grid (16,16,3). OpenBLAS kc=384 panel
// chains (fl(fl(S1+S2)+S3)) — q/k bit-identical. BK=32, double-buffered LDS.
// ---------------------------------------------------------------------------
__global__ __launch_bounds__(256) void gemm_qkv(
    const float* __restrict__ A,
    const float* __restrict__ Wq, const float* __restrict__ Wk, const float* __restrict__ Wv,
    float* __restrict__ qo, float* __restrict__ ko, float* __restrict__ vo)
{
  const int z = blockIdx.z;
  const float* B = (z == 0) ? Wq : (z == 1) ? Wk : Wv;
  float* C = (z == 0) ? qo : (z == 1) ? ko : vo;

  const int bm = blockIdx.x * 64;
  const int bn = blockIdx.y * 64;
  const int tid = threadIdx.x;
  const int r0 = (tid >> 4) * 4;
  const int c0 = (tid & 15) * 4;

  __shared__ float As[2][32][68];
  __shared__ float Bs[2][32][64];

  float acc[4][4] = {};
  float tot[4][4] = {};

  const int ar = tid >> 2;
  const int ac = (tid & 3) * 8;
  const int br = tid >> 3;
  const int bc = (tid & 7) * 8;

  {
    float4 a0 = *(const float4*)(A + (long)(bm + ar) * 1024 + ac);
    float4 a1 = *(const float4*)(A + (long)(bm + ar) * 1024 + ac + 4);
    float4 b0 = *(const float4*)(B + (long)br * 1024 + bn + bc);
    float4 b1 = *(const float4*)(B + (long)br * 1024 + bn + bc + 4);
    As[0][ac + 0][ar] = a0.x; As[0][ac + 1][ar] = a0.y;
    As[0][ac + 2][ar] = a0.z; As[0][ac + 3][ar] = a0.w;
    As[0][ac + 4][ar] = a1.x; As[0][ac + 5][ar] = a1.y;
    As[0][ac + 6][ar] = a1.z; As[0][ac + 7][ar] = a1.w;
    *(float4*)&Bs[0][br][bc] = b0;
    *(float4*)&Bs[0][br][bc + 4] = b1;
  }
  __syncthreads();

  int cur = 0;
  for (int kt = 0; kt < 1024; kt += 32) {
    const bool more = (kt + 32 < 1024);
    float4 a0n, a1n, b0n, b1n;
    if (more) {
      a0n = *(const float4*)(A + (long)(bm + ar) * 1024 + kt + 32 + ac);
      a1n = *(const float4*)(A + (long)(bm + ar) * 1024 + kt + 32 + ac + 4);
      b0n = *(const float4*)(B + (long)(kt + 32 + br) * 1024 + bn + bc);
      b1n = *(const float4*)(B + (long)(kt + 32 + br) * 1024 + bn + bc + 4);
    }
    if (kt == 384 || kt == 768) {
#pragma unroll
      for (int e = 0; e < 4; ++e)
#pragma unroll
        for (int f = 0; f < 4; ++f) {
          tot[e][f] = __fadd_rn(tot[e][f], acc[e][f]);
          acc[e][f] = 0.0f;
        }
    }
#pragma unroll
    for (int kk = 0; kk < 32; ++kk) {
      const float4 xa = *(const float4*)&As[cur][kk][r0];
      const float4 yb = *(const float4*)&Bs[cur][kk][c0];
      acc[0][0] += xa.x * yb.x; acc[0][1] += xa.x * yb.y; acc[0][2] += xa.x * yb.z; acc[0][3] += xa.x * yb.w;
      acc[1][0] += xa.y * yb.x; acc[1][1] += xa.y * yb.y; acc[1][2] += xa.y * yb.z; acc[1][3] += xa.y * yb.w;
      acc[2][0] += xa.z * yb.x; acc[2][1] += xa.z * yb.y; acc[2][2] += xa.z * yb.z; acc[2][3] += xa.z * yb.w;
      acc[3][0] += xa.w * yb.x; acc[3][1] += xa.w * yb.y; acc[3][2] += xa.w * yb.z; acc[3][3] += xa.w * yb.w;
    }
    if (more) {
      const int nxt = cur ^ 1;
      As[nxt][ac + 0][ar] = a0n.x; As[nxt][ac + 1][ar] = a0n.y;
      As[nxt][ac + 2][ar] = a0n.z; As[nxt][ac + 3][ar] = a0n.w;
      As[nxt][ac + 4][ar] = a1n.x; As[nxt][ac + 5][ar] = a1n.y;
      As[nxt][ac + 6][ar] = a1n.z; As[nxt][ac + 7][ar] = a1n.w;
      *(float4*)&Bs[nxt][br][bc] = b0n;
      *(float4*)&Bs[nxt][br][bc + 4] = b1n;
      __syncthreads();
      cur = nxt;
    }
  }

#pragma unroll
  for (int e = 0; e < 4; ++e)
#pragma unroll
    for (int f = 0; f < 4; ++f)
      C[(long)(bm + r0 + e) * 1024 + bn + c0 + f] = __fadd_rn(tot[e][f], acc[e][f]);
}

// ---------------------------------------------------------------------------
// Output projection GEMM, 32x64 tile (512 blocks), 2x4/thread, double-buffered.
// ---------------------------------------------------------------------------
__global__ __launch_bounds__(256) void gemm_out(
    const float* __restrict__ A, const float* __restrict__ B, float* __restrict__ C)
{
  const int bm = blockIdx.x * 32;
  const int bn = blockIdx.y * 64;
  const int tid = threadIdx.x;
  const int r0 = (tid >> 4) * 2;
  const int c0 = (tid & 15) * 4;

  __shared__ float As[2][16][36];
  __shared__ float Bs[2][16][64];

  float acc[2][4] = {};

  const int ar = tid >> 3;
  const int ac = (tid & 7) * 2;
  const int br = tid >> 4;
  const int bc = (tid & 15) * 4;

  {
    float2 av = *(const float2*)(A + (long)(bm + ar) * 1024 + ac);
    float4 bv = *(const float4*)(B + (long)br * 1024 + bn + bc);
    As[0][ac + 0][ar] = av.x;
    As[0][ac + 1][ar] = av.y;
    *(float4*)&Bs[0][br][bc] = bv;
  }
  __syncthreads();

  int cur = 0;
  for (int kt = 0; kt < 1024; kt += 16) {
    const bool more = (kt + 16 < 1024);
    float2 avn;
    float4 bvn;
    if (more) {
      avn = *(const float2*)(A + (long)(bm + ar) * 1024 + kt + 16 + ac);
      bvn = *(const float4*)(B + (long)(kt + 16 + br) * 1024 + bn + bc);
    }
#pragma unroll
    for (int kk = 0; kk < 16; ++kk) {
      const float2 xa = *(const float2*)&As[cur][kk][r0];
      const float4 yb = *(const float4*)&Bs[cur][kk][c0];
      acc[0][0] += xa.x * yb.x; acc[0][1] += xa.x * yb.y; acc[0][2] += xa.x * yb.z; acc[0][3] += xa.x * yb.w;
      acc[1][0] += xa.y * yb.x; acc[1][1] += xa.y * yb.y; acc[1][2] += xa.y * yb.z; acc[1][3] += xa.y * yb.w;
    }
    if (more) {
      const int nxt = cur ^ 1;
      As[nxt][ac + 0][ar] = avn.x;
      As[nxt][ac + 1][ar] = avn.y;
      *(float4*)&Bs[nxt][br][bc] = bvn;
      __syncthreads();
      cur = nxt;
    }
  }

#pragma unroll
  for (int e = 0; e < 2; ++e)
#pragma unroll
    for (int f = 0; f < 4; ++f)
      C[(long)(bm + r0 + e) * 1024 + bn + c0 + f] = acc[e][f];
}

// ---------------------------------------------------------------------------
// RoPE in-place (f32, layout (s, h*64+d)), numpy-f32-faithful constants.
// ---------------------------------------------------------------------------
__global__ __launch_bounds__(256) void rope_kernel(float* __restrict__ q,
                                                   float* __restrict__ kb,
                                                   const int* __restrict__ pos_ids)
{
  const int g = blockIdx.x * blockDim.x + threadIdx.x;
  const int t = g & 31;
  const int h = (g >> 5) & 15;
  const int s = (g >> 9) & 1023;
  const int buf = g >> 19;
  float* p = buf ? kb : q;

  const float e = (float)(2 * t) / 64.0f;
  const float p32 = (float)pow(10000.0, (double)e);
  const float inv = __fdiv_rn(1.0f, p32);
  const float posf = (float)pos_ids[s];
  const float ang = __fmul_rn(posf, inv);
  const float c  = (float)cos((double)ang);
  const float sn = (float)sin((double)ang);

  const int base = s * 1024 + h * 64;
  const float x1 = p[base + t];
  const float x2 = p[base + t + 32];
  p[base + t]      = __fadd_rn(__fmul_rn(x1, c), __fmul_rn(-x2, sn));
  p[base + t + 32] = __fadd_rn(__fmul_rn(x2, c), __fmul_rn(x1, sn));
}

// ---------------------------------------------------------------------------
// Score GEMM, causal lower-triangle tiles (136 per head), grid (136, G).
// ---------------------------------------------------------------------------
__global__ __launch_bounds__(256) void gemm_score(
    const float* __restrict__ q, const float* __restrict__ kb,
    float* __restrict__ S, int headBase)
{
  const int x = blockIdx.x;
  int bmT = 0;
  while ((bmT + 1) * (bmT + 2) / 2 <= x) ++bmT;
  const int bnT = x - bmT * (bmT + 1) / 2;

  const int hl = blockIdx.y;
  const int off = (headBase + hl) * 64;
  const int bm = bmT * 64;
  const int bn = bnT * 64;
  const int tid = threadIdx.x;
  const int r0 = (tid >> 4) * 4;
  const int c0 = (tid & 15) * 4;

  __shared__ float As[16][68];
  __shared__ float Bs[16][68];

  float acc[4][4] = {};

  const int ar = tid >> 2;
  const int ac = (tid & 3) * 4;

  for (int kt = 0; kt < 64; kt += 16) {
    float4 av = *(const float4*)(q  + (long)(bm + ar) * 1024 + off + kt + ac);
    float4 bv = *(const float4*)(kb + (long)(bn + ar) * 1024 + off + kt + ac);
    As[ac + 0][ar] = av.x; As[ac + 1][ar] = av.y;
    As[ac + 2][ar] = av.z; As[ac + 3][ar] = av.w;
    Bs[ac + 0][ar] = bv.x; Bs[ac + 1][ar] = bv.y;
    Bs[ac + 2][ar] = bv.z; Bs[ac + 3][ar] = bv.w;
    __syncthreads();
#pragma unroll
    for (int kk = 0; kk < 16; ++kk) {
      const float4 xa = *(const float4*)&As[kk][r0];
      const float4 yb = *(const float4*)&Bs[kk][c0];
      acc[0][0] += xa.x * yb.x; acc[0][1] += xa.x * yb.y; acc[0][2] += xa.x * yb.z; acc[0][3] += xa.x * yb.w;
      acc[1][0] += xa.y * yb.x; acc[1][1] += xa.y * yb.y; acc[1][2] += xa.y * yb.z; acc[1][3] += xa.y * yb.w;
      acc[2][0] += xa.z * yb.x; acc[2][1] += xa.z * yb.y; acc[2][2] += xa.z * yb.z; acc[2][3] += xa.z * yb.w;
      acc[3][0] += xa.w * yb.x; acc[3][1] += xa.w * yb.y; acc[3][2] += xa.w * yb.z; acc[3][3] += xa.w * yb.w;
    }
    __syncthreads();
  }

#pragma unroll
  for (int e = 0; e < 4; ++e)
#pragma unroll
    for (int f = 0; f < 4; ++f)
      S[((long)hl * 1024 + bm + r0 + e) * 1024 + bn + c0 + f] = acc[e][f] * 0.125f;
}

// ---------------------------------------------------------------------------
// Selection (radix w/ shifted digits + early exits) + ambiguity +
// compacted-list aggregates (single-hypothesis fast path).
// One 256-thread block per (row i, local head hl). Selection bit-identical.
// ---------------------------------------------------------------------------
__global__ __launch_bounds__(256) void select_agg2(
    const float* __restrict__ S, const float* __restrict__ v,
    float* __restrict__ comb, int headBase)
{
  const int i = blockIdx.x;
  const int hl = blockIdx.y;
  const int h = headBase + hl;
  const int tid = threadIdx.x;
  const int lane = tid & 63;
  const int wid = tid >> 6;

  __shared__ int hist[256];
  __shared__ int wtot[4];
  __shared__ unsigned wmaxArr[4];
  __shared__ int selBinSh, newRkSh, selCntSh;
  __shared__ unsigned vminSh;
  __shared__ int mInIdx;
  __shared__ unsigned WBits;
  __shared__ int outIdxMin;
  __shared__ unsigned long long tbIn, tbOut;
  __shared__ int hypOut, hypIn;
  __shared__ int listLen;
  __shared__ unsigned list[128];
  __shared__ float red[6][4][64];

  if (tid == 0) {
    mInIdx = -1; WBits = 0u; outIdxMin = 0x7FFFFFFF;
    tbIn = ~0ull; tbOut = ~0ull; hypOut = -1; hypIn = -1; listLen = 0;
  }

  const int cs = (i + 255) >> 8;
  const int j0 = tid * cs;
  const int j1 = imin(j0 + cs, i);
  const int nj = (j1 > j0) ? (j1 - j0) : 0;

  float rawr[4];
  unsigned uf[4];
  const float* row = S + ((long)hl * 1024 + i) * 1024;
  unsigned umax = 0u;
  for (int m = 0; m < nj; ++m) {
    const float rv = row[j0 + m];
    rawr[m] = rv;
    const unsigned u = __float_as_uint((rv >= 0.2f) ? rv : 0.0f);
    uf[m] = u;
    umax = (u > umax) ? u : umax;
  }

  const int kk = (i > 0) ? (i + 9) / 10 : 0;
  unsigned V = 0u;
  int need_eq = 0;
  unsigned char f0[4] = {0, 0, 0, 0};

  if (kk > 0) {
    // block max of uf -> choose digit scheme
#pragma unroll
    for (int off = 32; off >= 1; off >>= 1) {
      unsigned o = (unsigned)__shfl_xor((int)umax, off, 64);
      umax = (o > umax) ? o : umax;
    }
    if (lane == 0) wmaxArr[wid] = umax;
    __syncthreads();
    unsigned bmax = wmaxArr[0];
    bmax = (wmaxArr[1] > bmax) ? wmaxArr[1] : bmax;
    bmax = (wmaxArr[2] > bmax) ? wmaxArr[2] : bmax;
    bmax = (wmaxArr[3] > bmax) ? wmaxArr[3] : bmax;
    const bool fastD = (bmax < 0x40000000u);   // all values in {0} U [0.2,2)

    // digit schedule: fast -> shifts {18,10,2,0} widths {8,8,8,2},
    //                 slow -> shifts {24,16,8,0} widths {8,8,8,8}
    int rk = kk;
    unsigned cmpVal = 0;      // actives satisfy (u >> cmpShift) == cmpVal
    int cmpShift = 0;
    bool done = false;
    for (int pass = 0; pass < 4 && !done; ++pass) {
      const int shift = fastD ? (pass == 0 ? 18 : pass == 1 ? 10 : pass == 2 ? 2 : 0)
                              : (24 - 8 * pass);
      const unsigned mask = (fastD && pass == 3) ? 0x3u : 0xFFu;
      hist[tid] = 0;
      __syncthreads();
      for (int m = 0; m < nj; ++m) {
        const unsigned u = uf[m];
        const bool active = (pass == 0) || ((u >> cmpShift) == cmpVal);
        if (active) atomicAdd(&hist[(u >> shift) & mask], 1);
      }
      __syncthreads();
      const int hval = hist[tid];
      int val = hval;
#pragma unroll
      for (int off = 1; off < 64; off <<= 1) {
        int n = __shfl_up(val, off, 64);
        if (lane >= off) val += n;
      }
      if (lane == 63) wtot[wid] = val;
      __syncthreads();
      int wpre = 0;
      for (int w = 0; w < wid; ++w) wpre += wtot[w];
      const int incl = wpre + val;
      const int total = wtot[0] + wtot[1] + wtot[2] + wtot[3];
      const int sfx = total - incl + hval;
      if (sfx >= rk && (sfx - hval) < rk) {
        selBinSh = tid;
        newRkSh = rk - (sfx - hval);
        selCntSh = hval;
      }
      __syncthreads();
      const int selBin = selBinSh;
      rk = newRkSh;
      const int scnt = selCntSh;
      // prefix value actives must match at test shift `shift`
      const unsigned hiseed = fastD ? (0x0Fu << 8) : 0u;
      const unsigned wbits = (fastD && pass == 3) ? 2u : 8u;
      const unsigned newCmp = ((pass == 0) ? hiseed : (cmpVal << wbits)) | (unsigned)selBin;
      if (pass == 0 && selBin == 0) {
        V = 0u; need_eq = rk; done = true;          // cut among exact zeros
      } else if (rk == scnt) {
        if (tid == 0) vminSh = 0xFFFFFFFFu;          // whole bin selected
        __syncthreads();
        for (int m = 0; m < nj; ++m)
          if (uf[m] != 0u && (uf[m] >> shift) == newCmp) atomicMin(&vminSh, uf[m]);
        __syncthreads();
        V = vminSh; need_eq = 0x3FFFFFFF; done = true;
      } else {
        cmpVal = newCmp;
        cmpShift = shift;
        if (pass == 3) { V = cmpVal; need_eq = rk; done = true; }  // shift==0 -> V=u
      }
    }

    // stable tie-break: exclusive count of V-equal elements before me
    int e = 0;
    for (int m = 0; m < nj; ++m)
      if (uf[m] == V) ++e;
    int val = e;
#pragma unroll
    for (int off = 1; off < 64; off <<= 1) {
      int n = __shfl_up(val, off, 64);
      if (lane >= off) val += n;
    }
    if (lane == 63) wtot[wid] = val;
    __syncthreads();
    int wpre = 0;
    for (int w = 0; w < wid; ++w) wpre += wtot[w];
    int excl = wpre + val - e;
    for (int m = 0; m < nj; ++m) {
      const unsigned u = uf[m];
      if (u > V) f0[m] = 1;
      else if (u == V) { if (excl < need_eq) f0[m] = 1; ++excl; }
    }
  }
  __syncthreads();

  if (kk > 0 && kk < i) {
    unsigned wmax = 0u;
    for (int m = 0; m < nj; ++m) {
      const int j = j0 + m;
      const unsigned u = uf[m];
      if (f0[m]) {
        if (u == V) atomicMax(&mInIdx, j);
        const float fv = __uint_as_float(u);
        const float dd = fv - 0.2f;
        if (fv >= 0.2f && dd < TAU)
          atomicMin(&tbIn, (((unsigned long long)__float_as_uint(dd)) << 32) | (unsigned)j);
      } else {
        wmax = (u > wmax) ? u : wmax;
        if (rawr[m] < 0.2f) {
          const float dd = 0.2f - rawr[m];
          if (dd < TAU)
            atomicMin(&tbOut, (((unsigned long long)__float_as_uint(dd)) << 32) | (unsigned)j);
        }
      }
    }
#pragma unroll
    for (int off = 32; off >= 1; off >>= 1) {
      unsigned o = (unsigned)__shfl_xor((int)wmax, off, 64);
      wmax = (o > wmax) ? o : wmax;
    }
    if (lane == 0) atomicMax(&WBits, wmax);
    __syncthreads();
    for (int m = 0; m < nj; ++m) {
      const int j = j0 + m;
      if (!f0[m] && uf[m] == WBits) atomicMin(&outIdxMin, j);
    }
    __syncthreads();
    if (tid == 0) {
      float bestD = TAU;
      int oI = -1, nI = -1;
      if (outIdxMin != 0x7FFFFFFF && mInIdx >= 0) {
        const float Vf = __uint_as_float(V);
        const float Wf = __uint_as_float(WBits);
        if (!(WBits == V && V == 0u)) {
          const float gapA = Vf - Wf;
          if (gapA < bestD) { bestD = gapA; oI = mInIdx; nI = outIdxMin; }
        }
        if (tbIn != ~0ull) {
          const float d = __uint_as_float((unsigned)(tbIn >> 32));
          const int jj = (int)(tbIn & 0xFFFFFFFFu);
          const bool noop = (WBits == 0u && jj < outIdxMin);
          if (!noop && d < bestD) { bestD = d; oI = jj; nI = outIdxMin; }
        }
        if (tbOut != ~0ull && Vf <= 0.2f) {
          const float d = __uint_as_float((unsigned)(tbOut >> 32));
          const int jj = (int)(tbOut & 0xFFFFFFFFu);
          if (d < bestD) { bestD = d; oI = mInIdx; nI = jj; }
        }
      }
      hypOut = oI; hypIn = nI;
    }
    __syncthreads();
  }

  const bool amb = (hypOut >= 0);
  int cnt = 0;
  unsigned ent[5];
  for (int m = 0; m < nj; ++m) {
    const int j = j0 + m;
    unsigned s1 = f0[m];
    if (amb) { if (j == hypOut) s1 = 0; if (j == hypIn) s1 = 1; }
    if (f0[m] | s1)
      ent[cnt++] = (unsigned)j | ((unsigned)f0[m] << 10) | (s1 << 11);
  }
  int val = cnt;
#pragma unroll
  for (int off = 1; off < 64; off <<= 1) {
    int n = __shfl_up(val, off, 64);
    if (lane >= off) val += n;
  }
  if (lane == 63) wtot[wid] = val;
  __syncthreads();
  int wpre = 0;
  for (int w = 0; w < wid; ++w) wpre += wtot[w];
  const int base = wpre + val - cnt;
  for (int c = 0; c < cnt; ++c) list[base + c] = ent[c];
  if (tid == 0) listLen = wtot[0] + wtot[1] + wtot[2] + wtot[3];
  __syncthreads();

  const int L = listLen;
  const float denom = (float)(kk > 0 ? kk : 1);
  float* crow = comb + ((long)(h * 1024 + i)) * 256;

  if (!amb) {
    // ---- single-hypothesis fast path (identical values: 0.5*(S+S)==S) ----
    float sum0 = 0, sq0 = 0, mx0 = NEGF;
    for (int e = wid; e < L; e += 4) {
      const int j = list[e] & 1023;
      const float vv = v[(long)j * 1024 + h * 64 + lane];
      sum0 += vv; sq0 += vv * vv; mx0 = fmaxf(mx0, vv);
    }
    red[0][wid][lane] = sum0; red[1][wid][lane] = sq0; red[2][wid][lane] = mx0;
    __syncthreads();
    if (tid < 64) {
      float S0 = 0, Q0 = 0, M0 = NEGF;
#pragma unroll
      for (int gg = 0; gg < 4; ++gg) {
        S0 += red[0][gg][tid]; Q0 += red[1][gg][tid]; M0 = fmaxf(M0, red[2][gg][tid]);
      }
      const float mean0 = S0 / denom;
      const float var0 = fmaxf(Q0 / denom - mean0 * mean0, 0.0f);
      crow[tid]       = S0;
      crow[64 + tid]  = mean0;
      crow[128 + tid] = (kk > 0) ? M0 : 0.0f;
      crow[192 + tid] = var0;
    }
  } else {
    float sum0 = 0, sq0 = 0, mx0 = NEGF, sum1 = 0, sq1 = 0, mx1 = NEGF;
    for (int e = wid; e < L; e += 4) {
      const unsigned en = list[e];
      const int j = en & 1023;
      const float vv = v[(long)j * 1024 + h * 64 + lane];
      if (en & (1u << 10)) { sum0 += vv; sq0 += vv * vv; mx0 = fmaxf(mx0, vv); }
      if (en & (1u << 11)) { sum1 += vv; sq1 += vv * vv; mx1 = fmaxf(mx1, vv); }
    }
    red[0][wid][lane] = sum0; red[1][wid][lane] = sq0; red[2][wid][lane] = mx0;
    red[3][wid][lane] = sum1; red[4][wid][lane] = sq1; red[5][wid][lane] = mx1;
    __syncthreads();
    if (tid < 64) {
      float S0 = 0, Q0 = 0, M0 = NEGF, S1 = 0, Q1 = 0, M1 = NEGF;
#pragma unroll
      for (int gg = 0; gg < 4; ++gg) {
        S0 += red[0][gg][tid]; Q0 += red[1][gg][tid]; M0 = fmaxf(M0, red[2][gg][tid]);
        S1 += red[3][gg][tid]; Q1 += red[4][gg][tid]; M1 = fmaxf(M1, red[5][gg][tid]);
      }
      const float mean0 = S0 / denom, mean1 = S1 / denom;
      const float var0 = fmaxf(Q0 / denom - mean0 * mean0, 0.0f);
      const float var1 = fmaxf(Q1 / denom - mean1 * mean1, 0.0f);
      const float mx0o = (kk > 0) ? M0 : 0.0f;
      const float mx1o = (kk > 0) ? M1 : 0.0f;
      crow[tid]       = 0.5f * (S0 + S1);
      crow[64 + tid]  = 0.5f * (mean0 + mean1);
      crow[128 + tid] = 0.5f * (mx0o + mx1o);
      crow[192 + tid] = 0.5f * (var0 + var1);
    }
  }
}

// ---------------------------------------------------------------------------
// Launch
// ---------------------------------------------------------------------------
extern "C" void kernel_launch(void* const* d_in, const int* in_sizes, int n_in,
                              void* d_out, int out_size, void* d_ws, size_t ws_size,
                              hipStream_t stream)
{
  const float* hidden = (const float*)d_in[0];
  const float* Wq = (const float*)d_in[1];
  const float* Wk = (const float*)d_in[2];
  const float* Wv = (const float*)d_in[3];
  const float* Wo = (const float*)d_in[4];
  const float* W1 = (const float*)d_in[5];
  const float* W2 = (const float*)d_in[6];
  const float* eps = (const float*)d_in[7];
  const int* pos = (const int*)d_in[8];

  const size_t MB = 1024UL * 1024UL;
  int G = 4;
  if (ws_size >= 28 * MB + 64 * MB) G = 16;
  else if (ws_size >= 28 * MB + 32 * MB) G = 8;

  float* q      = (float*)d_ws;
  float* kbuf   = q + (1 << 20);
  float* v      = kbuf + (1 << 20);
  float* comb   = v + (1 << 20);
  float* scores = comb + (1 << 22);
  float* h1     = scores;               // overlay (scores dead after select)
  float* ho     = scores + (1 << 21);

  const dim3 blk(256);

  gemm_qkv<<<dim3(16, 16, 3), blk, 0, stream>>>(hidden, Wq, Wk, Wv, q, kbuf, v);

  rope_kernel<<<4096, blk, 0, stream>>>(q, kbuf, pos);

  for (int g = 0; g < 16; g += G) {
    gemm_score<<<dim3(136, G), blk, 0, stream>>>(q, kbuf, scores, g);
    select_agg2<<<dim3(1024, G), blk, 0, stream>>>(scores, v, comb, g);
  }

  gemm64<1><<<dim3(16, 2, 16), blk, 0, stream>>>(comb, W1, h1, nullptr, nullptr,
      1024, 128, 256, 256, 128, 128, (long)1024 * 256, (long)256 * 128, (long)1024 * 128);

  gemm64<2><<<dim3(16, 1, 16), blk, 0, stream>>>(h1, W2, ho, v, eps,
      1024, 64, 128, 128, 64, 1024, (long)1024 * 128, (long)128 * 64, 64);

  gemm_out<<<dim3(32, 16), blk, 0, stream>>>(ho, Wo, (float*)d_out);
}

// Round 19
// 398.400 us; speedup vs baseline: 1.0172x; 1.0172x over previous
//
#include <hip/hip_runtime.h>
#include <math.h>

// ---------------------------------------------------------------------------
// b=1, S=1024, H=16, D=64, HID=1024. All f32; pos int32; out f32.
// Passing R10-R18 semantics (absmax 6.958e-3). This round (select_agg2 only):
//  (1) pass-0 zero-count wave aggregation: 4 atomics to hist[0] instead of
//      ~900 (zeros are ~90% of elements) — kills the LDS same-address pileup.
//  (2) skip tie-break scan when the whole bin is selected (f0 = u>=V exactly).
// Selection + output bit-identical.
// ---------------------------------------------------------------------------
#define NEGF  -1e30f
#define TAU   1e-6f

static __device__ __forceinline__ int imin(int a, int b) { return a < b ? a : b; }

// ---------------------------------------------------------------------------
// f32 GEMM, 64x64 tile, 256 threads, 4x4/thread, BK=16, sequential FMA over k.
// MODE 0: plain f32; 1: silu; 2: +eps*R residual. Batched via blockIdx.z.
// ---------------------------------------------------------------------------
template <int MODE>
__global__ __launch_bounds__(256) void gemm64(
    const float* __restrict__ A, const float* __restrict__ B, float* __restrict__ C,
    const float* __restrict__ R, const float* __restrict__ eps_p,
    int M, int N, int K, int lda, int ldb, int ldc,
    long sA, long sB, long sC)
{
  const int z = blockIdx.z;
  A += (long)z * sA;
  B += (long)z * sB;
  float* Cf = C + (long)z * sC;
  const float* Rz = (MODE == 2) ? (R + (long)z * sC) : nullptr;

  const int bm = blockIdx.x * 64;
  const int bn = blockIdx.y * 64;
  const int tid = threadIdx.x;
  const int r0 = (tid >> 4) * 4;
  const int c0 = (tid & 15) * 4;

  __shared__ float As[16][68];
  __shared__ float Bs[16][64];

  float acc[4][4] = {};

  const int ar = tid >> 2;
  const int ac = (tid & 3) * 4;
  const int br = tid >> 4;
  const int bc = (tid & 15) * 4;

  for (int kt = 0; kt < K; kt += 16) {
    float4 av = *(const float4*)(A + (long)(bm + ar) * lda + kt + ac);
    float4 bv = *(const float4*)(B + (long)(kt + br) * ldb + bn + bc);
    As[ac + 0][ar] = av.x;
    As[ac + 1][ar] = av.y;
    As[ac + 2][ar] = av.z;
    As[ac + 3][ar] = av.w;
    *(float4*)&Bs[br][bc] = bv;
    __syncthreads();
#pragma unroll
    for (int kk = 0; kk < 16; ++kk) {
      const float4 xa = *(const float4*)&As[kk][r0];
      const float4 yb = *(const float4*)&Bs[kk][c0];
      acc[0][0] += xa.x * yb.x; acc[0][1] += xa.x * yb.y; acc[0][2] += xa.x * yb.z; acc[0][3] += xa.x * yb.w;
      acc[1][0] += xa.y * yb.x; acc[1][1] += xa.y * yb.y; acc[1][2] += xa.y * yb.z; acc[1][3] += xa.y * yb.w;
      acc[2][0] += xa.z * yb.x; acc[2][1] += xa.z * yb.y; acc[2][2] += xa.z * yb.z; acc[2][3] += xa.z * yb.w;
      acc[3][0] += xa.w * yb.x; acc[3][1] += xa.w * yb.y; acc[3][2] += xa.w * yb.z; acc[3][3] += xa.w * yb.w;
    }
    __syncthreads();
  }

  const float ev = (MODE == 2) ? eps_p[0] : 0.0f;
#pragma unroll
  for (int e = 0; e < 4; ++e)
#pragma unroll
    for (int f = 0; f < 4; ++f) {
      const int r = bm + r0 + e;
      const int c = bn + c0 + f;
      float x = acc[e][f];
      if (MODE == 1) x = x / (1.0f + expf(-x));
      if (MODE == 2) x += ev * Rz[(long)r * ldc + c];
      Cf[(long)r * ldc + c] = x;
    }
}

// ---------------------------------------------------------------------------
// Fused QKV projection, 1024^3 x3, grid (16,16,3). OpenBLAS kc=384 panel
// chains (fl(fl(S1+S2)+S3)) — q/k bit-identical. BK=32, double-buffered LDS.
// ---------------------------------------------------------------------------
__global__ __launch_bounds__(256) void gemm_qkv(
    const float* __restrict__ A,
    const float* __restrict__ Wq, const float* __restrict__ Wk, const float* __restrict__ Wv,
    float* __restrict__ qo, float* __restrict__ ko, float* __restrict__ vo)
{
  const int z = blockIdx.z;
  const float* B = (z == 0) ? Wq : (z == 1) ? Wk : Wv;
  float* C = (z == 0) ? qo : (z == 1) ? ko : vo;

  const int bm = blockIdx.x * 64;
  const int bn = blockIdx.y * 64;
  const int tid = threadIdx.x;
  const int r0 = (tid >> 4) * 4;
  const int c0 = (tid & 15) * 4;

  __shared__ float As[2][32][68];
  __shared__ float Bs[2][32][64];

  float acc[4][4] = {};
  float tot[4][4] = {};

  const int ar = tid >> 2;
  const int ac = (tid & 3) * 8;
  const int br = tid >> 3;
  const int bc = (tid & 7) * 8;

  {
    float4 a0 = *(const float4*)(A + (long)(bm + ar) * 1024 + ac);
    float4 a1 = *(const float4*)(A + (long)(bm + ar) * 1024 + ac + 4);
    float4 b0 = *(const float4*)(B + (long)br * 1024 + bn + bc);
    float4 b1 = *(const float4*)(B + (long)br * 1024 + bn + bc + 4);
    As[0][ac + 0][ar] = a0.x; As[0][ac + 1][ar] = a0.y;
    As[0][ac + 2][ar] = a0.z; As[0][ac + 3][ar] = a0.w;
    As[0][ac + 4][ar] = a1.x; As[0][ac + 5][ar] = a1.y;
    As[0][ac + 6][ar] = a1.z; As[0][ac + 7][ar] = a1.w;
    *(float4*)&Bs[0][br][bc] = b0;
    *(float4*)&Bs[0][br][bc + 4] = b1;
  }
  __syncthreads();

  int cur = 0;
  for (int kt = 0; kt < 1024; kt += 32) {
    const bool more = (kt + 32 < 1024);
    float4 a0n, a1n, b0n, b1n;
    if (more) {
      a0n = *(const float4*)(A + (long)(bm + ar) * 1024 + kt + 32 + ac);
      a1n = *(const float4*)(A + (long)(bm + ar) * 1024 + kt + 32 + ac + 4);
      b0n = *(const float4*)(B + (long)(kt + 32 + br) * 1024 + bn + bc);
      b1n = *(const float4*)(B + (long)(kt + 32 + br) * 1024 + bn + bc + 4);
    }
    if (kt == 384 || kt == 768) {
#pragma unroll
      for (int e = 0; e < 4; ++e)
#pragma unroll
        for (int f = 0; f < 4; ++f) {
          tot[e][f] = __fadd_rn(tot[e][f], acc[e][f]);
          acc[e][f] = 0.0f;
        }
    }
#pragma unroll
    for (int kk = 0; kk < 32; ++kk) {
      const float4 xa = *(const float4*)&As[cur][kk][r0];
      const float4 yb = *(const float4*)&Bs[cur][kk][c0];
      acc[0][0] += xa.x * yb.x; acc[0][1] += xa.x * yb.y; acc[0][2] += xa.x * yb.z; acc[0][3] += xa.x * yb.w;
      acc[1][0] += xa.y * yb.x; acc[1][1] += xa.y * yb.y; acc[1][2] += xa.y * yb.z; acc[1][3] += xa.y * yb.w;
      acc[2][0] += xa.z * yb.x; acc[2][1] += xa.z * yb.y; acc[2][2] += xa.z * yb.z; acc[2][3] += xa.z * yb.w;
      acc[3][0] += xa.w * yb.x; acc[3][1] += xa.w * yb.y; acc[3][2] += xa.w * yb.z; acc[3][3] += xa.w * yb.w;
    }
    if (more) {
      const int nxt = cur ^ 1;
      As[nxt][ac + 0][ar] = a0n.x; As[nxt][ac + 1][ar] = a0n.y;
      As[nxt][ac + 2][ar] = a0n.z; As[nxt][ac + 3][ar] = a0n.w;
      As[nxt][ac + 4][ar] = a1n.x; As[nxt][ac + 5][ar] = a1n.y;
      As[nxt][ac + 6][ar] = a1n.z; As[nxt][ac + 7][ar] = a1n.w;
      *(float4*)&Bs[nxt][br][bc] = b0n;
      *(float4*)&Bs[nxt][br][bc + 4] = b1n;
      __syncthreads();
      cur = nxt;
    }
  }

#pragma unroll
  for (int e = 0; e < 4; ++e)
#pragma unroll
    for (int f = 0; f < 4; ++f)
      C[(long)(bm + r0 + e) * 1024 + bn + c0 + f] = __fadd_rn(tot[e][f], acc[e][f]);
}

// ---------------------------------------------------------------------------
// Output projection GEMM, 32x64 tile (512 blocks), 2x4/thread, double-buffered.
// ---------------------------------------------------------------------------
__global__ __launch_bounds__(256) void gemm_out(
    const float* __restrict__ A, const float* __restrict__ B, float* __restrict__ C)
{
  const int bm = blockIdx.x * 32;
  const int bn = blockIdx.y * 64;
  const int tid = threadIdx.x;
  const int r0 = (tid >> 4) * 2;
  const int c0 = (tid & 15) * 4;

  __shared__ float As[2][16][36];
  __shared__ float Bs[2][16][64];

  float acc[2][4] = {};

  const int ar = tid >> 3;
  const int ac = (tid & 7) * 2;
  const int br = tid >> 4;
  const int bc = (tid & 15) * 4;

  {
    float2 av = *(const float2*)(A + (long)(bm + ar) * 1024 + ac);
    float4 bv = *(const float4*)(B + (long)br * 1024 + bn + bc);
    As[0][ac + 0][ar] = av.x;
    As[0][ac + 1][ar] = av.y;
    *(float4*)&Bs[0][br][bc] = bv;
  }
  __syncthreads();

  int cur = 0;
  for (int kt = 0; kt < 1024; kt += 16) {
    const bool more = (kt + 16 < 1024);
    float2 avn;
    float4 bvn;
    if (more) {
      avn = *(const float2*)(A + (long)(bm + ar) * 1024 + kt + 16 + ac);
      bvn = *(const float4*)(B + (long)(kt + 16 + br) * 1024 + bn + bc);
    }
#pragma unroll
    for (int kk = 0; kk < 16; ++kk) {
      const float2 xa = *(const float2*)&As[cur][kk][r0];
      const float4 yb = *(const float4*)&Bs[cur][kk][c0];
      acc[0][0] += xa.x * yb.x; acc[0][1] += xa.x * yb.y; acc[0][2] += xa.x * yb.z; acc[0][3] += xa.x * yb.w;
      acc[1][0] += xa.y * yb.x; acc[1][1] += xa.y * yb.y; acc[1][2] += xa.y * yb.z; acc[1][3] += xa.y * yb.w;
    }
    if (more) {
      const int nxt = cur ^ 1;
      As[nxt][ac + 0][ar] = avn.x;
      As[nxt][ac + 1][ar] = avn.y;
      *(float4*)&Bs[nxt][br][bc] = bvn;
      __syncthreads();
      cur = nxt;
    }
  }

#pragma unroll
  for (int e = 0; e < 2; ++e)
#pragma unroll
    for (int f = 0; f < 4; ++f)
      C[(long)(bm + r0 + e) * 1024 + bn + c0 + f] = acc[e][f];
}

// ---------------------------------------------------------------------------
// RoPE in-place (f32, layout (s, h*64+d)), numpy-f32-faithful constants.
// ---------------------------------------------------------------------------
__global__ __launch_bounds__(256) void rope_kernel(float* __restrict__ q,
                                                   float* __restrict__ kb,
                                                   const int* __restrict__ pos_ids)
{
  const int g = blockIdx.x * blockDim.x + threadIdx.x;
  const int t = g & 31;
  const int h = (g >> 5) & 15;
  const int s = (g >> 9) & 1023;
  const int buf = g >> 19;
  float* p = buf ? kb : q;

  const float e = (float)(2 * t) / 64.0f;
  const float p32 = (float)pow(10000.0, (double)e);
  const float inv = __fdiv_rn(1.0f, p32);
  const float posf = (float)pos_ids[s];
  const float ang = __fmul_rn(posf, inv);
  const float c  = (float)cos((double)ang);
  const float sn = (float)sin((double)ang);

  const int base = s * 1024 + h * 64;
  const float x1 = p[base + t];
  const float x2 = p[base + t + 32];
  p[base + t]      = __fadd_rn(__fmul_rn(x1, c), __fmul_rn(-x2, sn));
  p[base + t + 32] = __fadd_rn(__fmul_rn(x2, c), __fmul_rn(x1, sn));
}

// ---------------------------------------------------------------------------
// Score GEMM, causal lower-triangle tiles (136 per head), grid (136, G).
// ---------------------------------------------------------------------------
__global__ __launch_bounds__(256) void gemm_score(
    const float* __restrict__ q, const float* __restrict__ kb,
    float* __restrict__ S, int headBase)
{
  const int x = blockIdx.x;
  int bmT = 0;
  while ((bmT + 1) * (bmT + 2) / 2 <= x) ++bmT;
  const int bnT = x - bmT * (bmT + 1) / 2;

  const int hl = blockIdx.y;
  const int off = (headBase + hl) * 64;
  const int bm = bmT * 64;
  const int bn = bnT * 64;
  const int tid = threadIdx.x;
  const int r0 = (tid >> 4) * 4;
  const int c0 = (tid & 15) * 4;

  __shared__ float As[16][68];
  __shared__ float Bs[16][68];

  float acc[4][4] = {};

  const int ar = tid >> 2;
  const int ac = (tid & 3) * 4;

  for (int kt = 0; kt < 64; kt += 16) {
    float4 av = *(const float4*)(q  + (long)(bm + ar) * 1024 + off + kt + ac);
    float4 bv = *(const float4*)(kb + (long)(bn + ar) * 1024 + off + kt + ac);
    As[ac + 0][ar] = av.x; As[ac + 1][ar] = av.y;
    As[ac + 2][ar] = av.z; As[ac + 3][ar] = av.w;
    Bs[ac + 0][ar] = bv.x; Bs[ac + 1][ar] = bv.y;
    Bs[ac + 2][ar] = bv.z; Bs[ac + 3][ar] = bv.w;
    __syncthreads();
#pragma unroll
    for (int kk = 0; kk < 16; ++kk) {
      const float4 xa = *(const float4*)&As[kk][r0];
      const float4 yb = *(const float4*)&Bs[kk][c0];
      acc[0][0] += xa.x * yb.x; acc[0][1] += xa.x * yb.y; acc[0][2] += xa.x * yb.z; acc[0][3] += xa.x * yb.w;
      acc[1][0] += xa.y * yb.x; acc[1][1] += xa.y * yb.y; acc[1][2] += xa.y * yb.z; acc[1][3] += xa.y * yb.w;
      acc[2][0] += xa.z * yb.x; acc[2][1] += xa.z * yb.y; acc[2][2] += xa.z * yb.z; acc[2][3] += xa.z * yb.w;
      acc[3][0] += xa.w * yb.x; acc[3][1] += xa.w * yb.y; acc[3][2] += xa.w * yb.z; acc[3][3] += xa.w * yb.w;
    }
    __syncthreads();
  }

#pragma unroll
  for (int e = 0; e < 4; ++e)
#pragma unroll
    for (int f = 0; f < 4; ++f)
      S[((long)hl * 1024 + bm + r0 + e) * 1024 + bn + c0 + f] = acc[e][f] * 0.125f;
}

// ---------------------------------------------------------------------------
// Selection (shifted radix + early exits + zero-count aggregation) +
// ambiguity + compacted-list aggregates. Selection bit-identical.
// ---------------------------------------------------------------------------
__global__ __launch_bounds__(256) void select_agg2(
    const float* __restrict__ S, const float* __restrict__ v,
    float* __restrict__ comb, int headBase)
{
  const int i = blockIdx.x;
  const int hl = blockIdx.y;
  const int h = headBase + hl;
  const int tid = threadIdx.x;
  const int lane = tid & 63;
  const int wid = tid >> 6;

  __shared__ int hist[256];
  __shared__ int wtot[4];
  __shared__ unsigned wmaxArr[4];
  __shared__ int selBinSh, newRkSh, selCntSh;
  __shared__ unsigned vminSh;
  __shared__ int mInIdx;
  __shared__ unsigned WBits;
  __shared__ int outIdxMin;
  __shared__ unsigned long long tbIn, tbOut;
  __shared__ int hypOut, hypIn;
  __shared__ int listLen;
  __shared__ unsigned list[128];
  __shared__ float red[6][4][64];

  if (tid == 0) {
    mInIdx = -1; WBits = 0u; outIdxMin = 0x7FFFFFFF;
    tbIn = ~0ull; tbOut = ~0ull; hypOut = -1; hypIn = -1; listLen = 0;
  }

  const int cs = (i + 255) >> 8;
  const int j0 = tid * cs;
  const int j1 = imin(j0 + cs, i);
  const int nj = (j1 > j0) ? (j1 - j0) : 0;

  float rawr[4];
  unsigned uf[4];
  const float* row = S + ((long)hl * 1024 + i) * 1024;
  unsigned umax = 0u;
  for (int m = 0; m < nj; ++m) {
    const float rv = row[j0 + m];
    rawr[m] = rv;
    const unsigned u = __float_as_uint((rv >= 0.2f) ? rv : 0.0f);
    uf[m] = u;
    umax = (u > umax) ? u : umax;
  }

  const int kk = (i > 0) ? (i + 9) / 10 : 0;
  unsigned V = 0u;
  int need_eq = 0;
  unsigned char f0[4] = {0, 0, 0, 0};

  if (kk > 0) {
    // block max of uf -> choose digit scheme
#pragma unroll
    for (int off = 32; off >= 1; off >>= 1) {
      unsigned o = (unsigned)__shfl_xor((int)umax, off, 64);
      umax = (o > umax) ? o : umax;
    }
    if (lane == 0) wmaxArr[wid] = umax;
    __syncthreads();
    unsigned bmax = wmaxArr[0];
    bmax = (wmaxArr[1] > bmax) ? wmaxArr[1] : bmax;
    bmax = (wmaxArr[2] > bmax) ? wmaxArr[2] : bmax;
    bmax = (wmaxArr[3] > bmax) ? wmaxArr[3] : bmax;
    const bool fastD = (bmax < 0x40000000u);   // all values in {0} U [0.2,2)

    int rk = kk;
    unsigned cmpVal = 0;
    int cmpShift = 0;
    bool done = false;
    for (int pass = 0; pass < 4 && !done; ++pass) {
      const int shift = fastD ? (pass == 0 ? 18 : pass == 1 ? 10 : pass == 2 ? 2 : 0)
                              : (24 - 8 * pass);
      const unsigned mask = (fastD && pass == 3) ? 0x3u : 0xFFu;
      hist[tid] = 0;
      __syncthreads();
      if (pass == 0) {
        // zeros aggregated per wave: 1 atomic to hist[0] per wave, not ~900
        int zc = 0;
        for (int m = 0; m < nj; ++m) {
          const unsigned u = uf[m];
          if (u == 0u) ++zc;
          else atomicAdd(&hist[(u >> shift) & mask], 1);
        }
#pragma unroll
        for (int off = 32; off >= 1; off >>= 1) zc += __shfl_xor(zc, off, 64);
        if (lane == 0 && zc) atomicAdd(&hist[0], zc);
      } else {
        for (int m = 0; m < nj; ++m) {
          const unsigned u = uf[m];
          if ((u >> cmpShift) == cmpVal) atomicAdd(&hist[(u >> shift) & mask], 1);
        }
      }
      __syncthreads();
      const int hval = hist[tid];
      int val = hval;
#pragma unroll
      for (int off = 1; off < 64; off <<= 1) {
        int n = __shfl_up(val, off, 64);
        if (lane >= off) val += n;
      }
      if (lane == 63) wtot[wid] = val;
      __syncthreads();
      int wpre = 0;
      for (int w = 0; w < wid; ++w) wpre += wtot[w];
      const int incl = wpre + val;
      const int total = wtot[0] + wtot[1] + wtot[2] + wtot[3];
      const int sfx = total - incl + hval;
      if (sfx >= rk && (sfx - hval) < rk) {
        selBinSh = tid;
        newRkSh = rk - (sfx - hval);
        selCntSh = hval;
      }
      __syncthreads();
      const int selBin = selBinSh;
      rk = newRkSh;
      const int scnt = selCntSh;
      const unsigned hiseed = fastD ? (0x0Fu << 8) : 0u;
      const unsigned wbits = (fastD && pass == 3) ? 2u : 8u;
      const unsigned newCmp = ((pass == 0) ? hiseed : (cmpVal << wbits)) | (unsigned)selBin;
      if (pass == 0 && selBin == 0) {
        V = 0u; need_eq = rk; done = true;            // cut among exact zeros
      } else if (rk == scnt) {
        if (tid == 0) vminSh = 0xFFFFFFFFu;            // whole bin selected
        __syncthreads();
        for (int m = 0; m < nj; ++m)
          if (uf[m] != 0u && (uf[m] >> shift) == newCmp) atomicMin(&vminSh, uf[m]);
        __syncthreads();
        V = vminSh; need_eq = 0x3FFFFFFF; done = true;
      } else {
        cmpVal = newCmp;
        cmpShift = shift;
        if (pass == 3) { V = cmpVal; need_eq = rk; done = true; }
      }
    }

    if (need_eq >= 0x3FFFFFFF) {
      // all V-ties selected: no stable scan needed
      for (int m = 0; m < nj; ++m)
        if (uf[m] >= V) f0[m] = 1;
    } else {
      // stable tie-break: exclusive count of V-equal elements before me
      int e = 0;
      for (int m = 0; m < nj; ++m)
        if (uf[m] == V) ++e;
      int val = e;
#pragma unroll
      for (int off = 1; off < 64; off <<= 1) {
        int n = __shfl_up(val, off, 64);
        if (lane >= off) val += n;
      }
      if (lane == 63) wtot[wid] = val;
      __syncthreads();
      int wpre = 0;
      for (int w = 0; w < wid; ++w) wpre += wtot[w];
      int excl = wpre + val - e;
      for (int m = 0; m < nj; ++m) {
        const unsigned u = uf[m];
        if (u > V) f0[m] = 1;
        else if (u == V) { if (excl < need_eq) f0[m] = 1; ++excl; }
      }
    }
  }
  __syncthreads();

  if (kk > 0 && kk < i) {
    unsigned wmax = 0u;
    for (int m = 0; m < nj; ++m) {
      const int j = j0 + m;
      const unsigned u = uf[m];
      if (f0[m]) {
        if (u == V) atomicMax(&mInIdx, j);
        const float fv = __uint_as_float(u);
        const float dd = fv - 0.2f;
        if (fv >= 0.2f && dd < TAU)
          atomicMin(&tbIn, (((unsigned long long)__float_as_uint(dd)) << 32) | (unsigned)j);
      } else {
        wmax = (u > wmax) ? u : wmax;
        if (rawr[m] < 0.2f) {
          const float dd = 0.2f - rawr[m];
          if (dd < TAU)
            atomicMin(&tbOut, (((unsigned long long)__float_as_uint(dd)) << 32) | (unsigned)j);
        }
      }
    }
#pragma unroll
    for (int off = 32; off >= 1; off >>= 1) {
      unsigned o = (unsigned)__shfl_xor((int)wmax, off, 64);
      wmax = (o > wmax) ? o : wmax;
    }
    if (lane == 0) atomicMax(&WBits, wmax);
    __syncthreads();
    for (int m = 0; m < nj; ++m) {
      const int j = j0 + m;
      if (!f0[m] && uf[m] == WBits) atomicMin(&outIdxMin, j);
    }
    __syncthreads();
    if (tid == 0) {
      float bestD = TAU;
      int oI = -1, nI = -1;
      if (outIdxMin != 0x7FFFFFFF && mInIdx >= 0) {
        const float Vf = __uint_as_float(V);
        const float Wf = __uint_as_float(WBits);
        if (!(WBits == V && V == 0u)) {
          const float gapA = Vf - Wf;
          if (gapA < bestD) { bestD = gapA; oI = mInIdx; nI = outIdxMin; }
        }
        if (tbIn != ~0ull) {
          const float d = __uint_as_float((unsigned)(tbIn >> 32));
          const int jj = (int)(tbIn & 0xFFFFFFFFu);
          const bool noop = (WBits == 0u && jj < outIdxMin);
          if (!noop && d < bestD) { bestD = d; oI = jj; nI = outIdxMin; }
        }
        if (tbOut != ~0ull && Vf <= 0.2f) {
          const float d = __uint_as_float((unsigned)(tbOut >> 32));
          const int jj = (int)(tbOut & 0xFFFFFFFFu);
          if (d < bestD) { bestD = d; oI = mInIdx; nI = jj; }
        }
      }
      hypOut = oI; hypIn = nI;
    }
    __syncthreads();
  }

  const bool amb = (hypOut >= 0);
  int cnt = 0;
  unsigned ent[5];
  for (int m = 0; m < nj; ++m) {
    const int j = j0 + m;
    unsigned s1 = f0[m];
    if (amb) { if (j == hypOut) s1 = 0; if (j == hypIn) s1 = 1; }
    if (f0[m] | s1)
      ent[cnt++] = (unsigned)j | ((unsigned)f0[m] << 10) | (s1 << 11);
  }
  int val = cnt;
#pragma unroll
  for (int off = 1; off < 64; off <<= 1) {
    int n = __shfl_up(val, off, 64);
    if (lane >= off) val += n;
  }
  if (lane == 63) wtot[wid] = val;
  __syncthreads();
  int wpre = 0;
  for (int w = 0; w < wid; ++w) wpre += wtot[w];
  const int base = wpre + val - cnt;
  for (int c = 0; c < cnt; ++c) list[base + c] = ent[c];
  if (tid == 0) listLen = wtot[0] + wtot[1] + wtot[2] + wtot[3];
  __syncthreads();

  const int L = listLen;
  const float denom = (float)(kk > 0 ? kk : 1);
  float* crow = comb + ((long)(h * 1024 + i)) * 256;

  if (!amb) {
    float sum0 = 0, sq0 = 0, mx0 = NEGF;
    for (int e = wid; e < L; e += 4) {
      const int j = list[e] & 1023;
      const float vv = v[(long)j * 1024 + h * 64 + lane];
      sum0 += vv; sq0 += vv * vv; mx0 = fmaxf(mx0, vv);
    }
    red[0][wid][lane] = sum0; red[1][wid][lane] = sq0; red[2][wid][lane] = mx0;
    __syncthreads();
    if (tid < 64) {
      float S0 = 0, Q0 = 0, M0 = NEGF;
#pragma unroll
      for (int gg = 0; gg < 4; ++gg) {
        S0 += red[0][gg][tid]; Q0 += red[1][gg][tid]; M0 = fmaxf(M0, red[2][gg][tid]);
      }
      const float mean0 = S0 / denom;
      const float var0 = fmaxf(Q0 / denom - mean0 * mean0, 0.0f);
      crow[tid]       = S0;
      crow[64 + tid]  = mean0;
      crow[128 + tid] = (kk > 0) ? M0 : 0.0f;
      crow[192 + tid] = var0;
    }
  } else {
    float sum0 = 0, sq0 = 0, mx0 = NEGF, sum1 = 0, sq1 = 0, mx1 = NEGF;
    for (int e = wid; e < L; e += 4) {
      const unsigned en = list[e];
      const int j = en & 1023;
      const float vv = v[(long)j * 1024 + h * 64 + lane];
      if (en & (1u << 10)) { sum0 += vv; sq0 += vv * vv; mx0 = fmaxf(mx0, vv); }
      if (en & (1u << 11)) { sum1 += vv; sq1 += vv * vv; mx1 = fmaxf(mx1, vv); }
    }
    red[0][wid][lane] = sum0; red[1][wid][lane] = sq0; red[2][wid][lane] = mx0;
    red[3][wid][lane] = sum1; red[4][wid][lane] = sq1; red[5][wid][lane] = mx1;
    __syncthreads();
    if (tid < 64) {
      float S0 = 0, Q0 = 0, M0 = NEGF, S1 = 0, Q1 = 0, M1 = NEGF;
#pragma unroll
      for (int gg = 0; gg < 4; ++gg) {
        S0 += red[0][gg][tid]; Q0 += red[1][gg][tid]; M0 = fmaxf(M0, red[2][gg][tid]);
        S1 += red[3][gg][tid]; Q1 += red[4][gg][tid]; M1 = fmaxf(M1, red[5][gg][tid]);
      }
      const float mean0 = S0 / denom, mean1 = S1 / denom;
      const float var0 = fmaxf(Q0 / denom - mean0 * mean0, 0.0f);
      const float var1 = fmaxf(Q1 / denom - mean1 * mean1, 0.0f);
      const float mx0o = (kk > 0) ? M0 : 0.0f;
      const float mx1o = (kk > 0) ? M1 : 0.0f;
      crow[tid]       = 0.5f * (S0 + S1);
      crow[64 + tid]  = 0.5f * (mean0 + mean1);
      crow[128 + tid] = 0.5f * (mx0o + mx1o);
      crow[192 + tid] = 0.5f * (var0 + var1);
    }
  }
}

// ---------------------------------------------------------------------------
// Launch
// ---------------------------------------------------------------------------
extern "C" void kernel_launch(void* const* d_in, const int* in_sizes, int n_in,
                              void* d_out, int out_size, void* d_ws, size_t ws_size,
                              hipStream_t stream)
{
  const float* hidden = (const float*)d_in[0];
  const float* Wq = (const float*)d_in[1];
  const float* Wk = (const float*)d_in[2];
  const float* Wv = (const float*)d_in[3];
  const float* Wo = (const float*)d_in[4];
  const float* W1 = (const float*)d_in[5];
  const float* W2 = (const float*)d_in[6];
  const float* eps = (const float*)d_in[7];
  const int* pos = (const int*)d_in[8];

  const size_t MB = 1024UL * 1024UL;
  int G = 4;
  if (ws_size >= 28 * MB + 64 * MB) G = 16;
  else if (ws_size >= 28 * MB + 32 * MB) G = 8;

  float* q      = (float*)d_ws;
  float* kbuf   = q + (1 << 20);
  float* v      = kbuf + (1 << 20);
  float* comb   = v + (1 << 20);
  float* scores = comb + (1 << 22);
  float* h1     = scores;               // overlay (scores dead after select)
  float* ho     = scores + (1 << 21);

  const dim3 blk(256);

  gemm_qkv<<<dim3(16, 16, 3), blk, 0, stream>>>(hidden, Wq, Wk, Wv, q, kbuf, v);

  rope_kernel<<<4096, blk, 0, stream>>>(q, kbuf, pos);

  for (int g = 0; g < 16; g += G) {
    gemm_score<<<dim3(136, G), blk, 0, stream>>>(q, kbuf, scores, g);
    select_agg2<<<dim3(1024, G), blk, 0, stream>>>(scores, v, comb, g);
  }

  gemm64<1><<<dim3(16, 2, 16), blk, 0, stream>>>(comb, W1, h1, nullptr, nullptr,
      1024, 128, 256, 256, 128, 128, (long)1024 * 256, (long)256 * 128, (long)1024 * 128);

  gemm64<2><<<dim3(16, 1, 16), blk, 0, stream>>>(h1, W2, ho, v, eps,
      1024, 64, 128, 128, 64, 1024, (long)1024 * 128, (long)128 * 64, 64);

  gemm_out<<<dim3(32, 16), blk, 0, stream>>>(ho, Wo, (float*)d_out);
}